// Round 3
// baseline (559.311 us; speedup 1.0000x reference)
//
#include <hip/hip_runtime.h>
#include <stdint.h>

// out[n] = features[n] @ W[inds[n]] + b[inds[n]],  N=1M, D=64, E=8, fp32.
//
// Design: block = 512 threads = 8 waves, wave w owns expert w.
//  - lane j of wave w holds column j of W[w] in 64 VGPRs (loaded once).
//  - each wave scans the block's token chunk: 1 coalesced inds load + __ballot
//    per 64 tokens -> 64-bit match mask, walked with scalar bit ops (uniform).
//  - Round 0->2: cooperative L2 prefetch 2 groups ahead (each wave warms its
//    8-row slice via 2 compiler-visible global_load_dwordx4 kept alive by
//    empty asm) + software-pipelined inds. 384 -> 246 us/dispatch.
//  - Round 2->3: the per-token feature-row broadcast moves from SMEM
//    (s_load_dwordx16 + lgkmcnt(0): out-of-order returns force a full exposed
//    round-trip per token, and the 64-SGPR row forbids double-buffering) to
//    WAVE-UNIFORM VMEM: 16x global_load_dwordx4 with all 64 lanes at the same
//    address. The coalescer merges each to one 16-B fetch broadcast to all
//    lanes (the SGPR broadcast, but on the VMEM pipe). vmcnt is IN-ORDER, so
//    the compiler emits counted per-use waits; 16 loads issue back-to-back so
//    latency is amortized across the row and covered by 3 waves/SIMD.
//    Compute = 64 v_fmac_f32 per token in 4 chains (128 issue cycles).

typedef float v4f  __attribute__((ext_vector_type(4)));

constexpr int D = 64;
constexpr int CHUNK = 512;   // tokens per block; N=1048576 -> grid=2048

__global__ __launch_bounds__(512, 3)   // ~160 VGPR budget: wreg 64 + row 64 + pf/misc
void moe_split_kernel(const float* __restrict__ features,
                      const int* __restrict__ inds,
                      const float* __restrict__ W,
                      const float* __restrict__ b,
                      float* __restrict__ out, int N) {
    const int w    = threadIdx.x >> 6;   // wave id == expert id
    const int lane = threadIdx.x & 63;   // output column j

    // W[w][k][lane] for k=0..63 -> 64 VGPRs (coalesced 256B loads, L2/L3-hot)
    float wreg[D];
    const float* Wp = W + (size_t)w * D * D + lane;
    #pragma unroll
    for (int k = 0; k < D; ++k) wreg[k] = Wp[k * D];
    const float breg = b[w * D + lane];

    const int base = blockIdx.x * CHUNK;
    const int end  = min(base + CHUNK, N);

    // L2-prefetch state: wave w owns rows [g + 8w, g + 8w + 8) of each group g.
    // Values never used; empty asm keeps the loads alive and compiler-visible.
    const int sliceOff = w * 8;
    v4f pa0{}, pa1{}, pb0{}, pb1{};

    auto issue_pf = [&](int g, v4f& c0, v4f& c1) {
        if (g < end && g + 64 <= N) {
            const float* pb = features + (size_t)(g + sliceOff) * D;
            c0 = *reinterpret_cast<const v4f*>(pb + lane * 4);
            c1 = *reinterpret_cast<const v4f*>(pb + 256 + lane * 4);
        }
    };

    // prologue: warm groups 0 and 1; pipeline inds for group 0
    issue_pf(base, pa0, pa1);
    issue_pf(base + 64, pb0, pb1);
    const int t0 = base + lane;
    int iv = (t0 < N) ? inds[t0] : -1;

    auto do_group = [&](int nb, v4f& c0, v4f& c1) {
        // consume the 2-groups-old prefetch, reissue for group nb+128
        asm volatile("" :: "v"(c0), "v"(c1));
        issue_pf(nb + 128, c0, c1);

        // software-pipelined inds load for the next group
        const int tn = nb + 64 + lane;
        const int ivn = (nb + 64 < end && tn < N) ? inds[tn] : -1;

        unsigned long long mask = __ballot(iv == w);
        while (mask) {
            const int i = __builtin_ctzll(mask);
            mask &= mask - 1;
            const int n = nb + i;                       // wave-uniform
            // Wave-uniform address: every lane loads the same 16 B -> one
            // fetch, broadcast on return. 16 independent dwordx4 loads issue
            // back-to-back; in-order vmcnt gives counted per-use waits.
            const v4f* fp = reinterpret_cast<const v4f*>(features + (size_t)n * D);

            v4f r[16];
            #pragma unroll
            for (int c = 0; c < 16; ++c) r[c] = fp[c];

            float a0 = breg, a1 = 0.f, a2 = 0.f, a3 = 0.f;  // 4 fma chains
            #pragma unroll
            for (int c = 0; c < 16; ++c) {
                a0 = __builtin_fmaf(r[c][0], wreg[4*c+0], a0);
                a1 = __builtin_fmaf(r[c][1], wreg[4*c+1], a1);
                a2 = __builtin_fmaf(r[c][2], wreg[4*c+2], a2);
                a3 = __builtin_fmaf(r[c][3], wreg[4*c+3], a3);
            }
            out[(size_t)n * D + lane] = (a0 + a1) + (a2 + a3);  // coalesced 256B store
        }
        iv = ivn;
    };

    for (int nb = base; nb < end; nb += 128) {
        do_group(nb, pa0, pa1);
        if (nb + 64 < end) do_group(nb + 64, pb0, pb1);
    }
}

extern "C" void kernel_launch(void* const* d_in, const int* in_sizes, int n_in,
                              void* d_out, int out_size, void* d_ws, size_t ws_size,
                              hipStream_t stream) {
    const float* features = (const float*)d_in[0];
    const int*   inds     = (const int*)d_in[1];
    const float* W        = (const float*)d_in[2];
    const float* b        = (const float*)d_in[3];
    float*       out      = (float*)d_out;

    const int N = in_sizes[0] / D;       // 1048576
    const int grid = (N + CHUNK - 1) / CHUNK;
    moe_split_kernel<<<grid, 512, 0, stream>>>(features, inds, W, b, out, N);
}